// Round 1
// baseline (85.719 us; speedup 1.0000x reference)
//
#include <hip/hip_runtime.h>
#include <hip/hip_bf16.h>

// EdgeLearnGNN: B=16, N=64, F=1024, K=13, C=2
// Pipeline: pairwise weighted-L1 -> softmax(adj) -> (adj+I)@x -> Linear(F,F)
//           -> BN1(channels) -> Conv1d(N->1,k=1) -> Conv1d(1,1,13,SAME) -> BN2 -> relu -> head softmax
// Outputs: probs [16,2] (32 f32) then adj [16,64,64] (65536 f32)

typedef __attribute__((ext_vector_type(8))) __bf16 bf16x8;
typedef __attribute__((ext_vector_type(4))) float f32x4;

__device__ __forceinline__ unsigned short f2bf(float f) {
  union { float f; unsigned int u; } v; v.f = f;
  unsigned int r = v.u + 0x7FFFu + ((v.u >> 16) & 1u);   // RNE, finite values only
  return (unsigned short)(r >> 16);
}

// K1: blocks 0..255: partial weighted-L1 scores over a 64-wide f tile.
//     blocks 256..1279: convert gin_W (1M f32) to bf16.
__global__ __launch_bounds__(256) void k1_spart_conv(
    const float* __restrict__ x, const float* __restrict__ w,
    const float* __restrict__ gin_W,
    float* __restrict__ spart, unsigned short* __restrict__ ginWb) {
  int t = threadIdx.x;
  int bid = blockIdx.x;
  if (bid >= 256) {
    int idx = ((bid - 256) * 256 + t) * 4;
    float4 v = *reinterpret_cast<const float4*>(&gin_W[idx]);
    ushort4 u;
    u.x = f2bf(v.x); u.y = f2bf(v.y); u.z = f2bf(v.z); u.w = f2bf(v.w);
    *reinterpret_cast<ushort4*>(&ginWb[idx]) = u;
    return;
  }
  __shared__ __align__(16) float xt[64 * 68];   // stride 68 -> 2-way-free bank pattern
  __shared__ __align__(16) float wt[64];
  int b = bid >> 4, ft = bid & 15;
  int f0 = ft * 64;
  for (int c = 0; c < 16; ++c) {
    int idx = c * 256 + t;
    int n = idx >> 6, f = idx & 63;
    xt[n * 68 + f] = x[b * 65536 + n * 1024 + f0 + f];
  }
  if (t < 64) wt[t] = w[f0 + t];
  __syncthreads();
  int i0 = (t >> 4) * 4, j0 = (t & 15) * 4;
  float acc[4][4];
#pragma unroll
  for (int ii = 0; ii < 4; ++ii)
#pragma unroll
    for (int jj = 0; jj < 4; ++jj) acc[ii][jj] = 0.f;
  for (int f = 0; f < 64; f += 4) {
    float4 wv = *reinterpret_cast<const float4*>(&wt[f]);
    float4 av[4], bv[4];
#pragma unroll
    for (int ii = 0; ii < 4; ++ii) av[ii] = *reinterpret_cast<const float4*>(&xt[(i0 + ii) * 68 + f]);
#pragma unroll
    for (int jj = 0; jj < 4; ++jj) bv[jj] = *reinterpret_cast<const float4*>(&xt[(j0 + jj) * 68 + f]);
#pragma unroll
    for (int ii = 0; ii < 4; ++ii)
#pragma unroll
      for (int jj = 0; jj < 4; ++jj) {
        acc[ii][jj] += fabsf(av[ii].x - bv[jj].x) * wv.x
                     + fabsf(av[ii].y - bv[jj].y) * wv.y
                     + fabsf(av[ii].z - bv[jj].z) * wv.z
                     + fabsf(av[ii].w - bv[jj].w) * wv.w;
      }
  }
  float* out = spart + (size_t)bid * 4096;    // bid = b*16 + ft
#pragma unroll
  for (int ii = 0; ii < 4; ++ii)
#pragma unroll
    for (int jj = 0; jj < 4; ++jj)
      out[(i0 + ii) * 64 + (j0 + jj)] = acc[ii][jj];
}

// K2: sum 16 f-tile partials -> s; e = exp(-relu(s)); softmax over i (column-wise); adj -> d_out
__global__ __launch_bounds__(256) void k2_adj(
    const float* __restrict__ spart, float* __restrict__ dout) {
  __shared__ float es[64 * 65];
  __shared__ float csum[4][64];
  __shared__ float cinv[64];
  int t = threadIdx.x, b = blockIdx.x;
  float v[16];
#pragma unroll
  for (int c = 0; c < 16; ++c) v[c] = 0.f;
  for (int ft = 0; ft < 16; ++ft) {
    const float* p = spart + (size_t)(b * 16 + ft) * 4096;
#pragma unroll
    for (int c = 0; c < 16; ++c) v[c] += p[c * 256 + t];
  }
#pragma unroll
  for (int c = 0; c < 16; ++c) {
    int idx = c * 256 + t;
    int i = idx >> 6, j = idx & 63;
    es[i * 65 + j] = expf(-fmaxf(v[c], 0.f));
  }
  __syncthreads();
  {
    int j = t & 63, q = t >> 6;
    float s = 0.f;
    for (int i = q * 16; i < q * 16 + 16; ++i) s += es[i * 65 + j];
    csum[q][j] = s;
  }
  __syncthreads();
  if (t < 64) cinv[t] = 1.f / (csum[0][t] + csum[1][t] + csum[2][t] + csum[3][t]);
  __syncthreads();
  float* adj = dout + 32 + (size_t)b * 4096;
#pragma unroll
  for (int c = 0; c < 16; ++c) {
    int idx = c * 256 + t;
    int i = idx >> 6, j = idx & 63;
    adj[idx] = es[i * 65 + j] * cinv[j];
  }
}

// K3: h1[b,i,f] = x[b,i,f] + sum_j adj[b,i,j]*x[b,j,f], written as bf16
__global__ __launch_bounds__(256) void k3_h1(
    const float* __restrict__ x, const float* __restrict__ dout,
    unsigned short* __restrict__ h1) {
  __shared__ float adjs[64 * 65];
  __shared__ __align__(16) float xt[64 * 68];
  int t = threadIdx.x, bid = blockIdx.x;
  int b = bid >> 4, ft = bid & 15, f0 = ft * 64;
  const float* adj = dout + 32 + (size_t)b * 4096;
  for (int c = 0; c < 16; ++c) {
    int idx = c * 256 + t;
    int i = idx >> 6, j = idx & 63;
    adjs[i * 65 + j] = adj[idx];
    xt[i * 68 + j] = x[b * 65536 + i * 1024 + f0 + j];
  }
  __syncthreads();
  int i0 = (t >> 4) * 4, fl = (t & 15) * 4;
  float4 acc[4];
#pragma unroll
  for (int ii = 0; ii < 4; ++ii)
    acc[ii] = *reinterpret_cast<const float4*>(&xt[(i0 + ii) * 68 + fl]);  // identity term
  for (int j = 0; j < 64; ++j) {
    float4 xv = *reinterpret_cast<const float4*>(&xt[j * 68 + fl]);
#pragma unroll
    for (int ii = 0; ii < 4; ++ii) {
      float a = adjs[(i0 + ii) * 65 + j];
      acc[ii].x += a * xv.x; acc[ii].y += a * xv.y;
      acc[ii].z += a * xv.z; acc[ii].w += a * xv.w;
    }
  }
#pragma unroll
  for (int ii = 0; ii < 4; ++ii) {
    ushort4 u;
    u.x = f2bf(acc[ii].x); u.y = f2bf(acc[ii].y);
    u.z = f2bf(acc[ii].z); u.w = f2bf(acc[ii].w);
    *reinterpret_cast<ushort4*>(&h1[(size_t)(b * 64 + i0 + ii) * 1024 + f0 + fl]) = u;
  }
}

// K4: h2[r,o] = sum_f h1[r,f]*W[o,f] + gin_b[o]   (M=N=K=1024, bf16 MFMA 16x16x32)
// 256 blocks of 4 waves; wave = 16 rows x 64 cols; fragments loaded direct from L2.
__global__ __launch_bounds__(256) void k4_gemm(
    const unsigned short* __restrict__ h1, const unsigned short* __restrict__ Wb,
    const float* __restrict__ gin_b, float* __restrict__ h2) {
  int t = threadIdx.x;
  int wave = t >> 6, lane = t & 63;
  int bid = blockIdx.x;
  int rb = bid >> 4, cb = bid & 15;
  int rowbase = rb * 64 + wave * 16;
  int colbase = cb * 64;
  int lrow = lane & 15;     // A-row / B-col within 16-tile
  int kg = lane >> 4;       // k-group: 8 contiguous k per lane
  const unsigned short* ap = h1 + (size_t)(rowbase + lrow) * 1024 + kg * 8;
  const unsigned short* bp = Wb + (size_t)(colbase + lrow) * 1024 + kg * 8;
  f32x4 acc[4] = {{0.f,0.f,0.f,0.f},{0.f,0.f,0.f,0.f},{0.f,0.f,0.f,0.f},{0.f,0.f,0.f,0.f}};
#pragma unroll 4
  for (int ks = 0; ks < 32; ++ks) {
    bf16x8 a = *reinterpret_cast<const bf16x8*>(ap + ks * 32);
#pragma unroll
    for (int c = 0; c < 4; ++c) {
      bf16x8 bb = *reinterpret_cast<const bf16x8*>(bp + c * 16 * 1024 + ks * 32);
      acc[c] = __builtin_amdgcn_mfma_f32_16x16x32_bf16(a, bb, acc[c], 0, 0, 0);
    }
  }
  int drow = rowbase + kg * 4;      // C/D: row = (lane>>4)*4 + reg, col = lane&15
#pragma unroll
  for (int c = 0; c < 4; ++c) {
    int col = colbase + c * 16 + lrow;
    float gb = gin_b[col];
#pragma unroll
    for (int r = 0; r < 4; ++r)
      h2[(size_t)(drow + r) * 1024 + col] = acc[c][r] + gb;
  }
}

// K5: per-channel-n BN1 moments over (b, o): 16 rows x 1024
__global__ __launch_bounds__(256) void k5_stats(
    const float* __restrict__ h2, float* __restrict__ stats) {
  int n = blockIdx.x, t = threadIdx.x;
  float s = 0.f, s2 = 0.f;
  for (int b = 0; b < 16; ++b) {
    const float* row = h2 + (size_t)(b * 64 + n) * 1024;
    for (int f = t; f < 1024; f += 256) { float v = row[f]; s += v; s2 += v * v; }
  }
  __shared__ float rs[256], rs2[256];
  rs[t] = s; rs2[t] = s2;
  __syncthreads();
  for (int off = 128; off > 0; off >>= 1) {
    if (t < off) { rs[t] += rs[t + off]; rs2[t] += rs2[t + off]; }
    __syncthreads();
  }
  if (t == 0) {
    float m = rs[0] * (1.f / 16384.f);
    float var = rs2[0] * (1.f / 16384.f) - m * m;     // biased, as jnp.var
    stats[2 * n] = m;
    stats[2 * n + 1] = 1.f / sqrtf(var + 1e-5f);
  }
}

// K6: y[b,f] = sum_n c[n]*h2[b,n,f] + const0 (BN1+lc folded); conv1d k=13 SAME; BN2 partial moments
__global__ __launch_bounds__(256) void k6_y(
    const float* __restrict__ h2, const float* __restrict__ stats,
    const float* __restrict__ lc_W, const float* __restrict__ lc_b,
    const float* __restrict__ bn1_g, const float* __restrict__ bn1_b,
    const float* __restrict__ conv_W, const float* __restrict__ conv_b,
    float* __restrict__ y2, float* __restrict__ bn2part) {
  __shared__ float cls[64], dds[64];
  __shared__ __align__(16) float yr[1040];   // [0..7]=0, [8..1031]=y, [1032..1039]=0
  __shared__ float red[256], red2[256];
  __shared__ float c0s;
  int t = threadIdx.x, b = blockIdx.x;
  if (t < 64) {
    float m = stats[2 * t], inv = stats[2 * t + 1];
    float g = bn1_g[t], be = bn1_b[t], lw = lc_W[t];
    cls[t] = lw * g * inv;
    dds[t] = lw * (be - m * inv * g);
  }
  if (t < 8) { yr[t] = 0.f; yr[1032 + t] = 0.f; }
  __syncthreads();
  if (t == 0) {
    float s = 0.f;
    for (int n = 0; n < 64; ++n) s += dds[n];
    c0s = s + lc_b[0];
  }
  __syncthreads();
  int f0 = t * 4;
  float c0 = c0s;
  float4 acc = make_float4(c0, c0, c0, c0);
  for (int n = 0; n < 64; ++n) {
    float c = cls[n];
    float4 hv = *reinterpret_cast<const float4*>(&h2[(size_t)(b * 64 + n) * 1024 + f0]);
    acc.x += c * hv.x; acc.y += c * hv.y; acc.z += c * hv.z; acc.w += c * hv.w;
  }
  *reinterpret_cast<float4*>(&yr[8 + f0]) = acc;
  __syncthreads();
  float cw[13];
#pragma unroll
  for (int k = 0; k < 13; ++k) cw[k] = conv_W[k];
  float cb = conv_b[0];
  float s = 0.f, s2 = 0.f;
  float ov[4];
#pragma unroll
  for (int u = 0; u < 4; ++u) {
    int f = f0 + u;
    float v = cb;
#pragma unroll
    for (int k = 0; k < 13; ++k) v += yr[f + 2 + k] * cw[k];  // yr[8 + f - 6 + k]
    ov[u] = v; s += v; s2 += v * v;
  }
  *reinterpret_cast<float4*>(&y2[b * 1024 + f0]) = make_float4(ov[0], ov[1], ov[2], ov[3]);
  red[t] = s; red2[t] = s2;
  __syncthreads();
  for (int off = 128; off > 0; off >>= 1) {
    if (t < off) { red[t] += red[t + off]; red2[t] += red2[t + off]; }
    __syncthreads();
  }
  if (t == 0) { bn2part[2 * b] = red[0]; bn2part[2 * b + 1] = red2[0]; }
}

// K7: BN2 finalize + relu + head GEMV (16x1024x2) + 2-class softmax -> d_out[0..31]
__global__ __launch_bounds__(256) void k7_head(
    const float* __restrict__ y2, const float* __restrict__ bn2part,
    const float* __restrict__ bn2_g, const float* __restrict__ bn2_b,
    const float* __restrict__ out_W, const float* __restrict__ out_b,
    float* __restrict__ dout) {
  int t = threadIdx.x;
  float S = 0.f, S2 = 0.f;
  for (int b = 0; b < 16; ++b) { S += bn2part[2 * b]; S2 += bn2part[2 * b + 1]; }
  float m2 = S * (1.f / 16384.f);
  float inv2 = 1.f / sqrtf(S2 * (1.f / 16384.f) - m2 * m2 + 1e-5f);
  float g2 = bn2_g[0] * inv2, be2 = bn2_b[0];
  int b = t >> 4, seg = t & 15;
  float a0 = 0.f, a1 = 0.f;
  for (int f = seg * 64; f < seg * 64 + 64; ++f) {
    float v = (y2[b * 1024 + f] - m2) * g2 + be2;
    v = fmaxf(v, 0.f);
    a0 += v * out_W[f];
    a1 += v * out_W[1024 + f];
  }
  __shared__ float r0[256], r1[256];
  r0[t] = a0; r1[t] = a1;
  __syncthreads();
  for (int off = 8; off > 0; off >>= 1) {
    if (seg < off) { r0[t] += r0[t + off]; r1[t] += r1[t + off]; }
    __syncthreads();
  }
  if (seg == 0) {
    float l0 = r0[t] + out_b[0], l1 = r1[t] + out_b[1];
    float mx = fmaxf(l0, l1);
    float e0 = expf(l0 - mx), e1 = expf(l1 - mx);
    float inv = 1.f / (e0 + e1);
    dout[b * 2 + 0] = e0 * inv;
    dout[b * 2 + 1] = e1 * inv;
  }
}

extern "C" void kernel_launch(void* const* d_in, const int* in_sizes, int n_in,
                              void* d_out, int out_size, void* d_ws, size_t ws_size,
                              hipStream_t stream) {
  (void)in_sizes; (void)n_in; (void)out_size; (void)ws_size;
  const float* x      = (const float*)d_in[0];
  const float* w      = (const float*)d_in[1];
  const float* gin_W  = (const float*)d_in[2];
  const float* gin_b  = (const float*)d_in[3];
  const float* bn1_g  = (const float*)d_in[4];
  const float* bn1_b  = (const float*)d_in[5];
  const float* lc_W   = (const float*)d_in[6];
  const float* lc_b   = (const float*)d_in[7];
  const float* conv_W = (const float*)d_in[8];
  const float* conv_b = (const float*)d_in[9];
  const float* bn2_g  = (const float*)d_in[10];
  const float* bn2_b  = (const float*)d_in[11];
  const float* out_W  = (const float*)d_in[12];
  const float* out_b  = (const float*)d_in[13];
  float* dout = (float*)d_out;

  char* ws = (char*)d_ws;
  float* buf0 = (float*)ws;                                        // 4 MB: spart (K1/K2), then h2 (K4+)
  unsigned short* h1    = (unsigned short*)(ws + (4u << 20));      // 2 MB bf16
  unsigned short* ginWb = (unsigned short*)(ws + (6u << 20));      // 2 MB bf16
  float* stats   = (float*)(ws + (8u << 20));                      // 128 f32
  float* y2      = (float*)(ws + (8u << 20) + 4096);               // 16K f32
  float* bn2part = (float*)(ws + (8u << 20) + 4096 + 65536);       // 32 f32

  k1_spart_conv<<<dim3(1280), dim3(256), 0, stream>>>(x, w, gin_W, buf0, ginWb);
  k2_adj       <<<dim3(16),   dim3(256), 0, stream>>>(buf0, dout);
  k3_h1        <<<dim3(256),  dim3(256), 0, stream>>>(x, dout, h1);
  k4_gemm      <<<dim3(256),  dim3(256), 0, stream>>>(h1, ginWb, gin_b, buf0);
  k5_stats     <<<dim3(64),   dim3(256), 0, stream>>>(buf0, stats);
  k6_y         <<<dim3(16),   dim3(256), 0, stream>>>(buf0, stats, lc_W, lc_b, bn1_g, bn1_b,
                                                      conv_W, conv_b, y2, bn2part);
  k7_head      <<<dim3(1),    dim3(256), 0, stream>>>(y2, bn2part, bn2_g, bn2_b, out_W, out_b, dout);
}